// Round 2
// baseline (119.685 us; speedup 1.0000x reference)
//
#include <hip/hip_runtime.h>

// B=8, Cin=64, H=W=128, Cout=64, 9 bilinear taps at (i+0.4, j+0.4) == exact 4x4
// conv with zero pad. Implicit GEMM, bf16 MFMA 16x16x32.
//
// v5: strip=2, no intermediate buffer.
//   - Post-mortem: ~86 us of dur_us is harness poison fills; our budget was
//     21 us (v3) / 27 us (v4). v4's xb round-trip (HBM write + LLC re-read,
//     kernel-boundary fence flushes L2) cost more than DMA staging saved.
//   - v5: single conv kernel, 2 output rows/block (512 blk x 256 thr, 4 waves).
//     Stages 5 rows fp32->bf16 for 2 rows out: fetch amplification 2.5x (was
//     4x); per-pass per-XCD band ~2.5 MB < 4 MB L2 -> redundancy is L2-served.
//   - Wave split by Cout: wave = 128 px x 32 Cout, acc[8][2]. B-stream L2
//     traffic per MFMA halved (2 frags/rs instead of 4, reused 8x).
//   - Non-temporal out stores: 33.5 MB write stream bypasses L2, stops
//     evicting the x band.
//   - 512 blocks = exactly 2 blocks/CU co-resident (LDS 42.2 KB): no tail,
//     cross-block stage/compute overlap per SIMD.
//   - Same pass/rs/MFMA order as v3/v4 -> bitwise-identical output.

#define CIN   64
#define COUT  64
#define HH    128
#define WW    128

typedef __attribute__((ext_vector_type(8))) short bf16x8;   // 8 bf16 = 4 VGPRs
typedef __attribute__((ext_vector_type(4))) float f32x4;
typedef __attribute__((ext_vector_type(4))) unsigned int u32x4;

__device__ __forceinline__ unsigned short f2bf(float f) {
  unsigned int u = __float_as_uint(f);
  u = (u + 0x7fffu + ((u >> 16) & 1u)) >> 16;   // RNE
  return (unsigned short)u;
}

// ---------------------------------------------------------------------------
// W4[o][c][r][s] = sum_k w[o,c,k] * cy_k(r-iy_k) * cx_k(s-ix_k).
// Stream layout: wb2[(((p*16+rs)*4 + n)*64 + lane)*8 + j]; consuming lane l
// holds o = n*16 + (l&15), ch = p*32 + (l>>4)*8 + j, for tap rs. (verified)
// ---------------------------------------------------------------------------
__global__ void make_wb(const float* __restrict__ wgt,
                        const float* __restrict__ off,
                        unsigned short* __restrict__ wb2)
{
  int id = blockIdx.x * 64 + threadIdx.x;       // 4096 = 64*64
  int o = id >> 6, c = id & 63;
  float W16[16];
  #pragma unroll
  for (int i = 0; i < 16; ++i) W16[i] = 0.f;
  for (int k = 0; k < 9; ++k) {
    float dy = off[2*k], dx = off[2*k+1];
    float fyf = floorf(dy), fxf = floorf(dx);
    int   iy = (int)fyf,   ix = (int)fxf;       // in {0,1,2}
    float fy = dy - fyf,   fx = dx - fxf;
    float wk = wgt[(o*CIN + c)*9 + k];
    W16[(iy  )*4 + ix  ] += wk * (1.f-fy)*(1.f-fx);
    W16[(iy  )*4 + ix+1] += wk * (1.f-fy)*fx;
    W16[(iy+1)*4 + ix  ] += wk * fy*(1.f-fx);
    W16[(iy+1)*4 + ix+1] += wk * fy*fx;
  }
  int p = c >> 5, q = (c >> 3) & 3, j = c & 7;
  int n = o >> 4, m15 = o & 15;
  int lanei = q*16 + m15;
  for (int rs = 0; rs < 16; ++rs)
    wb2[(size_t)(((p*16 + rs)*4 + n)*64 + lanei)*8 + j] = f2bf(W16[rs]);
}

// ---------------------------------------------------------------------------
// conv: WG = 256 threads (4 waves), tile = 2 output rows x 128 px x 64 Cout.
// Wave (yr, ohalf): yr = out row in strip, ohalf = Cout half.
// LDS tile: 5 rows x 132 cols x 32 ch(bf16), XOR slot swizzle. 42240 B.
// ---------------------------------------------------------------------------
__global__ __launch_bounds__(256, 2)   // 2 waves/EU -> 2 blocks/CU (exact fit)
void conv_mfma(const float* __restrict__ x,
               const unsigned short* __restrict__ wb2,
               float* __restrict__ out)
{
  __shared__ unsigned short tile[5 * 132 * 32]; // 42240 B (also epilogue f32 buf)

  const int wg  = blockIdx.x;                   // 512
  const int xcd = wg & 7;
  const int i   = wg >> 3;                      // 0..63
  const int b   = i >> 3;
  const int ss  = i & 7;
  const int y0  = xcd * 16 + ss * 2;            // first out row of strip
  const int t     = threadIdx.x;
  const int wave  = t >> 6;                     // 0..3
  const int lane  = t & 63;
  const int m15   = lane & 15;
  const int q     = lane >> 4;
  const int yr    = wave >> 1;                  // 0..1: out row within strip
  const int ohalf = wave & 1;                   // 0..1: Cout half

  f32x4 acc[8][2];
  #pragma unroll
  for (int mi = 0; mi < 8; ++mi)
    #pragma unroll
    for (int nn = 0; nn < 2; ++nn)
      acc[mi][nn] = (f32x4){0.f, 0.f, 0.f, 0.f};

  #pragma unroll
  for (int p = 0; p < 2; ++p) {                 // channel pass: c in [32p, 32p+32)
    if (p) __syncthreads();                     // pass-0 tile reads complete

    if (p == 0 && t < 160) {                    // zero edge cells (cols 0,129,130,131)
      int row = t >> 5, rem = t & 31;
      int csel = rem >> 3;
      int col  = (csel == 0) ? 0 : (128 + csel);
      int w8   = rem & 7;
      *(unsigned long long*)&tile[(row*132 + col)*32 + w8*4] = 0ull;
    }

    // ---- stage: 40 segs = 5 rows x 4 chunks(8ch) x 2 x-halves ----
    #pragma unroll 2
    for (int it = 0; it < 10; ++it) {
      int g     = it*4 + wave;                  // 0..39
      int row   = g >> 3;                       // 0..4
      int rem   = g & 7;
      int chunk = rem >> 1;                     // 8-ch chunk within pass
      int xh    = rem & 1;
      int px    = xh*64 + lane;                 // 0..127
      int gy    = y0 + row - 1;                 // -1..129
      int pos   = px + 1;
      int slot  = (chunk + (pos >> 2)) & 3;     // XOR bank swizzle
      if ((unsigned)gy < (unsigned)HH) {
        const float* ps = x + ((size_t)((b*CIN + p*32 + chunk*8)*HH + gy))*WW + px;
        float v[8];
        #pragma unroll
        for (int cc = 0; cc < 8; ++cc) v[cc] = ps[(size_t)cc*HH*WW];
        unsigned int pk[4];
        #pragma unroll
        for (int ii = 0; ii < 4; ++ii)
          pk[ii] = (unsigned int)f2bf(v[2*ii]) | ((unsigned int)f2bf(v[2*ii+1]) << 16);
        *(u32x4*)&tile[((row*132 + pos)*4 + slot)*8] = *(u32x4*)pk;
      } else if (p == 0) {                      // OOB row: zero once; pass 1 keeps it
        *(u32x4*)&tile[((row*132 + pos)*4 + slot)*8] = (u32x4){0u,0u,0u,0u};
      }
    }
    __syncthreads();

    // ---- compute: 16 rs steps; B = contiguous stream loads, A = swizzled LDS ----
    const unsigned short* wstream = wb2 + (size_t)p*32768 + lane*8;
    #pragma unroll
    for (int rs = 0; rs < 16; ++rs) {
      const int r = rs >> 2, s = rs & 3;
      bf16x8 bfr[2];
      #pragma unroll
      for (int nn = 0; nn < 2; ++nn)
        bfr[nn] = *(const bf16x8*)(wstream + (rs*4 + ohalf*2 + nn)*512);
      bf16x8 afr[8];
      #pragma unroll
      for (int mi = 0; mi < 8; ++mi) {
        int pos  = mi*16 + m15 + s;
        int slot = (q + (pos >> 2)) & 3;
        afr[mi] = *(const bf16x8*)(&tile[(((yr + r)*132 + pos)*4 + slot)*8]);
      }
      #pragma unroll
      for (int mi = 0; mi < 8; ++mi)
        #pragma unroll
        for (int nn = 0; nn < 2; ++nn)
          acc[mi][nn] = __builtin_amdgcn_mfma_f32_16x16x32_bf16(afr[mi], bfr[nn], acc[mi][nn], 0, 0, 0);
    }
  }

  // ---- epilogue: per out row, transpose through LDS, NT stores ----
  float* epi = (float*)tile;                    // [64 o][132 px] = 33792 B
  #pragma unroll
  for (int yr2 = 0; yr2 < 2; ++yr2) {
    __syncthreads();                            // tile/epi reads complete
    if (yr == yr2) {
      #pragma unroll
      for (int mi = 0; mi < 8; ++mi)
        #pragma unroll
        for (int nn = 0; nn < 2; ++nn) {
          int o  = (ohalf*2 + nn)*16 + m15;
          int px = mi*16 + q*4;                 // D row = q*4 + reg
          *(f32x4*)&epi[o*132 + px] = acc[mi][nn];
        }
    }
    __syncthreads();
    #pragma unroll
    for (int ii = 0; ii < 8; ++ii) {
      int o  = ii*8 + (t >> 5);
      int px = (t & 31) * 4;
      f32x4 v = *(const f32x4*)&epi[o*132 + px];
      __builtin_nontemporal_store(v,
          (f32x4*)&out[(((size_t)(b*COUT + o))*HH + (y0 + yr2))*WW + px]);
    }
  }
}

// ---------------------------------------------------------------------------
extern "C" void kernel_launch(void* const* d_in, const int* in_sizes, int n_in,
                              void* d_out, int out_size, void* d_ws, size_t ws_size,
                              hipStream_t stream)
{
  const float* x   = (const float*)d_in[0];   // [8,64,128,128] fp32
  const float* wgt = (const float*)d_in[1];   // [64,64,9] fp32
  const float* off = (const float*)d_in[2];   // [9,2] fp32
  float* out = (float*)d_out;                 // [8,64,128,128] fp32
  unsigned short* wb2 = (unsigned short*)d_ws;// 128 KB stream-layout weights

  make_wb<<<64, 64, 0, stream>>>(wgt, off, wb2);
  conv_mfma<<<512, 256, 0, stream>>>(x, wb2, out);
}

// Round 3
// 117.923 us; speedup vs baseline: 1.0149x; 1.0149x over previous
//
#include <hip/hip_runtime.h>

// B=8, Cin=64, H=W=128, Cout=64, 9 bilinear taps at (i+0.4, j+0.4) == exact 4x4
// conv with zero pad. Implicit GEMM, bf16 MFMA 16x16x32.
//
// v6: occupancy restore.
//   - v5 post-mortem: FETCH 36 MB (L2 absorbs halo redundancy - keep), but
//     Occupancy 18% / MfmaUtil 12% / HBM 2.1 TB/s: latency-bound, 2 blocks/CU
//     can't overlap stage and compute. NT stores wrote 63.5 MB (1.9x ampl).
//   - v6: strip = 1 row x 64 px, 128 thr (2 waves = 2 Cout halves, acc[4][2]).
//     LDS 17408 B -> 8 blocks/CU, 16 waves/CU, 4 waves/SIMD (launch_bounds 4).
//     Grid 2048 = exact full residency; halo cols staged from neighbor data.
//   - Regular f32x4 stores (write-back L2, full lines) instead of NT.
//   - Same pass/rs/MFMA order + f2bf -> bitwise-identical output to v5.

#define CIN   64
#define COUT  64
#define HH    128
#define WW    128
#define NC    68    // tile cols: col c <-> global x = x0 - 1 + c, c in [0,66]

typedef __attribute__((ext_vector_type(8))) short bf16x8;   // 8 bf16 = 4 VGPRs
typedef __attribute__((ext_vector_type(4))) float f32x4;
typedef __attribute__((ext_vector_type(4))) unsigned int u32x4;

__device__ __forceinline__ unsigned short f2bf(float f) {
  unsigned int u = __float_as_uint(f);
  u = (u + 0x7fffu + ((u >> 16) & 1u)) >> 16;   // RNE
  return (unsigned short)u;
}

// ---------------------------------------------------------------------------
// W4[o][c][r][s] = sum_k w[o,c,k] * cy_k(r-iy_k) * cx_k(s-ix_k).
// Stream layout: wb2[(((p*16+rs)*4 + n)*64 + lane)*8 + j]; consuming lane l
// holds o = n*16 + (l&15), ch = p*32 + (l>>4)*8 + j, for tap rs. (verified)
// ---------------------------------------------------------------------------
__global__ void make_wb(const float* __restrict__ wgt,
                        const float* __restrict__ off,
                        unsigned short* __restrict__ wb2)
{
  int id = blockIdx.x * 64 + threadIdx.x;       // 4096 = 64*64
  int o = id >> 6, c = id & 63;
  float W16[16];
  #pragma unroll
  for (int i = 0; i < 16; ++i) W16[i] = 0.f;
  for (int k = 0; k < 9; ++k) {
    float dy = off[2*k], dx = off[2*k+1];
    float fyf = floorf(dy), fxf = floorf(dx);
    int   iy = (int)fyf,   ix = (int)fxf;       // in {0,1,2}
    float fy = dy - fyf,   fx = dx - fxf;
    float wk = wgt[(o*CIN + c)*9 + k];
    W16[(iy  )*4 + ix  ] += wk * (1.f-fy)*(1.f-fx);
    W16[(iy  )*4 + ix+1] += wk * (1.f-fy)*fx;
    W16[(iy+1)*4 + ix  ] += wk * fy*(1.f-fx);
    W16[(iy+1)*4 + ix+1] += wk * fy*fx;
  }
  int p = c >> 5, q = (c >> 3) & 3, j = c & 7;
  int n = o >> 4, m15 = o & 15;
  int lanei = q*16 + m15;
  for (int rs = 0; rs < 16; ++rs)
    wb2[(size_t)(((p*16 + rs)*4 + n)*64 + lanei)*8 + j] = f2bf(W16[rs]);
}

// ---------------------------------------------------------------------------
// conv: WG = 128 threads (2 waves), tile = 1 out row x 64 px x 64 Cout.
// Wave = 64 px x 32 Cout (wave index = Cout half), acc[4][2].
// LDS: 4 rows x 68 cols x 32 ch bf16, XOR slot swizzle. 17408 B -> 8 blk/CU.
// ---------------------------------------------------------------------------
__global__ __launch_bounds__(128, 4)   // 4 waves/EU -> 8 blocks/CU
void conv_mfma(const float* __restrict__ x,
               const unsigned short* __restrict__ wb2,
               float* __restrict__ out)
{
  __shared__ __align__(16) unsigned short tile[4 * NC * 32]; // 17408 B

  const int wg  = blockIdx.x;                   // 2048
  const int xcd = wg & 7;
  const int i   = wg >> 3;                      // 0..255
  const int b   = i >> 5;                       // 0..7
  const int r5  = i & 31;
  const int y0  = xcd * 16 + (r5 >> 1);         // XCD-local 16-row band
  const int x0  = (r5 & 1) * 64;                // x half
  const int t    = threadIdx.x;
  const int wave = t >> 6;                      // 0..1: Cout half
  const int lane = t & 63;
  const int m15  = lane & 15;
  const int q    = lane >> 4;

  f32x4 acc[4][2];
  #pragma unroll
  for (int mi = 0; mi < 4; ++mi)
    #pragma unroll
    for (int nn = 0; nn < 2; ++nn)
      acc[mi][nn] = (f32x4){0.f, 0.f, 0.f, 0.f};

  #pragma unroll
  for (int p = 0; p < 2; ++p) {                 // channel pass: c in [32p, 32p+32)
    if (p) __syncthreads();                     // pass-0 tile reads complete

    // ---- stage: 16 items = 4 rows x 4 chunks(8ch); 8 items per wave ----
    #pragma unroll
    for (int it = 0; it < 8; ++it) {
      int g     = it*2 + wave;                  // 0..15
      int row   = g >> 2;                       // 0..3
      int chunk = g & 3;                        // 8-ch chunk within pass
      int gy    = y0 + row - 1;                 // -1..129

      // main: col = lane (0..63), gx = x0 - 1 + lane
      {
        int gx   = x0 - 1 + lane;
        int slot = (chunk + (lane >> 2)) & 3;   // XOR bank swizzle
        unsigned short* dst = &tile[((row*NC + lane)*4 + slot)*8];
        if (((unsigned)gy < (unsigned)HH) && ((unsigned)gx < (unsigned)WW)) {
          const float* ps = x + ((size_t)(b*CIN + p*32 + chunk*8)*HH + gy)*WW + gx;
          float v[8];
          #pragma unroll
          for (int cc = 0; cc < 8; ++cc) v[cc] = ps[(size_t)cc*HH*WW];
          unsigned int pk[4];
          #pragma unroll
          for (int ii = 0; ii < 4; ++ii)
            pk[ii] = (unsigned int)f2bf(v[2*ii]) | ((unsigned int)f2bf(v[2*ii+1]) << 16);
          *(u32x4*)dst = *(u32x4*)pk;
        } else if (p == 0) {                    // OOB: zero once; pass 1 keeps it
          *(u32x4*)dst = (u32x4){0u,0u,0u,0u};
        }
      }
      // halo: lanes 0..2 -> col 64..66, gx = x0 + 63 + lane
      if (lane < 3) {
        int col  = 64 + lane;
        int gx   = x0 + 63 + lane;
        int slot = (chunk + (col >> 2)) & 3;
        unsigned short* dst = &tile[((row*NC + col)*4 + slot)*8];
        if (((unsigned)gy < (unsigned)HH) && ((unsigned)gx < (unsigned)WW)) {
          const float* ps = x + ((size_t)(b*CIN + p*32 + chunk*8)*HH + gy)*WW + gx;
          float v[8];
          #pragma unroll
          for (int cc = 0; cc < 8; ++cc) v[cc] = ps[(size_t)cc*HH*WW];
          unsigned int pk[4];
          #pragma unroll
          for (int ii = 0; ii < 4; ++ii)
            pk[ii] = (unsigned int)f2bf(v[2*ii]) | ((unsigned int)f2bf(v[2*ii+1]) << 16);
          *(u32x4*)dst = *(u32x4*)pk;
        } else if (p == 0) {
          *(u32x4*)dst = (u32x4){0u,0u,0u,0u};
        }
      }
    }
    __syncthreads();

    // ---- compute: 16 rs steps; B = contiguous stream loads, A = swizzled LDS ----
    const unsigned short* wstream = wb2 + (size_t)p*32768 + (size_t)lane*8;
    #pragma unroll
    for (int rs = 0; rs < 16; ++rs) {
      const int r = rs >> 2, s = rs & 3;
      bf16x8 bfr[2];
      #pragma unroll
      for (int nn = 0; nn < 2; ++nn)
        bfr[nn] = *(const bf16x8*)(wstream + (rs*4 + wave*2 + nn)*512);
      bf16x8 afr[4];
      #pragma unroll
      for (int mi = 0; mi < 4; ++mi) {
        int c    = mi*16 + m15 + s;             // 0..66
        int slot = (q + (c >> 2)) & 3;
        afr[mi] = *(const bf16x8*)&tile[((r*NC + c)*4 + slot)*8];
      }
      #pragma unroll
      for (int mi = 0; mi < 4; ++mi)
        #pragma unroll
        for (int nn = 0; nn < 2; ++nn)
          acc[mi][nn] = __builtin_amdgcn_mfma_f32_16x16x32_bf16(afr[mi], bfr[nn], acc[mi][nn], 0, 0, 0);
    }
  }

  // ---- epilogue: transpose through LDS for coalesced f32x4 stores ----
  __syncthreads();                              // all tile reads done
  float* epi = (float*)tile;                    // [64 o][68 px] f32 = 17408 B
  #pragma unroll
  for (int mi = 0; mi < 4; ++mi)
    #pragma unroll
    for (int nn = 0; nn < 2; ++nn) {
      int o  = (wave*2 + nn)*16 + m15;
      int px = mi*16 + q*4;                     // D row = q*4 + reg
      *(f32x4*)&epi[o*NC + px] = acc[mi][nn];
    }
  __syncthreads();
  #pragma unroll
  for (int round = 0; round < 8; ++round) {
    int idx = round*512 + t*4;                  // 64 o x 64 px
    int o = idx >> 6, px = idx & 63;
    f32x4 v = *(const f32x4*)&epi[o*NC + px];
    *(f32x4*)&out[(((size_t)(b*COUT + o))*HH + y0)*WW + x0 + px] = v;
  }
}

// ---------------------------------------------------------------------------
extern "C" void kernel_launch(void* const* d_in, const int* in_sizes, int n_in,
                              void* d_out, int out_size, void* d_ws, size_t ws_size,
                              hipStream_t stream)
{
  const float* x   = (const float*)d_in[0];   // [8,64,128,128] fp32
  const float* wgt = (const float*)d_in[1];   // [64,64,9] fp32
  const float* off = (const float*)d_in[2];   // [9,2] fp32
  float* out = (float*)d_out;                 // [8,64,128,128] fp32
  unsigned short* wb2 = (unsigned short*)d_ws;// 128 KB stream-layout weights

  make_wb<<<64, 64, 0, stream>>>(wgt, off, wb2);
  conv_mfma<<<2048, 128, 0, stream>>>(x, wb2, out);
}

// Round 4
// 107.109 us; speedup vs baseline: 1.1174x; 1.1010x over previous
//
#include <hip/hip_runtime.h>

// B=8, Cin=64, H=W=128, Cout=64, 9 bilinear taps at (i+0.4, j+0.4) == exact 4x4
// conv with zero pad. Implicit GEMM, bf16 MFMA 16x16x32.
//
// v7: VALU diet (structure identical to v6: 1 row x 64 px x 64 Cout, 128 thr,
//     2 waves = Cout halves, 8 blocks/CU).
//   - v6 post-mortem: ~3900 VALU inst/lane (VALUBusy 30%) = f2bf chains +
//     per-rs LDS address math + per-load 64b address chains. VALU-bound.
//   - cvt_pk: v_cvt_pk_bf16_f32 (RNE, bit-identical to f2bf) converts+packs
//     2 elems in 1 op. OOB-x via clamped address + cndmask on packed words.
//   - LDS addressing fully hoisted: XOR slot invariant under mi*16 and row
//     steps -> A-read = aptr[s] + r*4352 + mi*1024 (imm offsets, 0 VALU/rs);
//     stage store = pst[it&1] + row*4352 (+4096 for halo, same slot phase).
//   - staging base scalarized via readfirstlane(wave): SGPR base + single
//     per-lane voffset -> global_load saddr form.
//   - same pass/rs/MFMA order -> bitwise-identical output.

#define CIN   64
#define COUT  64
#define HH    128
#define WW    128
#define NC    68    // tile cols: col c <-> global x = x0 - 1 + c, c in [0,66]

typedef __attribute__((ext_vector_type(8))) short bf16x8;   // 8 bf16 = 4 VGPRs
typedef __attribute__((ext_vector_type(4))) float f32x4;
typedef __attribute__((ext_vector_type(4))) unsigned int u32x4;

__device__ __forceinline__ unsigned short f2bf(float f) {
  unsigned int u = __float_as_uint(f);
  u = (u + 0x7fffu + ((u >> 16) & 1u)) >> 16;   // RNE
  return (unsigned short)u;
}

__device__ __forceinline__ unsigned int cvtpk(float lo, float hi) {
  unsigned int r;                                // D = {bf16(lo), bf16(hi)} RNE
  asm("v_cvt_pk_bf16_f32 %0, %1, %2" : "=v"(r) : "v"(lo), "v"(hi));
  return r;
}

// ---------------------------------------------------------------------------
// W4[o][c][r][s] = sum_k w[o,c,k] * cy_k(r-iy_k) * cx_k(s-ix_k).
// Stream layout: wb2[(((p*16+rs)*4 + n)*64 + lane)*8 + j]; consuming lane l
// holds o = n*16 + (l&15), ch = p*32 + (l>>4)*8 + j, for tap rs. (verified)
// ---------------------------------------------------------------------------
__global__ void make_wb(const float* __restrict__ wgt,
                        const float* __restrict__ off,
                        unsigned short* __restrict__ wb2)
{
  int id = blockIdx.x * 64 + threadIdx.x;       // 4096 = 64*64
  int o = id >> 6, c = id & 63;
  float W16[16];
  #pragma unroll
  for (int i = 0; i < 16; ++i) W16[i] = 0.f;
  for (int k = 0; k < 9; ++k) {
    float dy = off[2*k], dx = off[2*k+1];
    float fyf = floorf(dy), fxf = floorf(dx);
    int   iy = (int)fyf,   ix = (int)fxf;       // in {0,1,2}
    float fy = dy - fyf,   fx = dx - fxf;
    float wk = wgt[(o*CIN + c)*9 + k];
    W16[(iy  )*4 + ix  ] += wk * (1.f-fy)*(1.f-fx);
    W16[(iy  )*4 + ix+1] += wk * (1.f-fy)*fx;
    W16[(iy+1)*4 + ix  ] += wk * fy*(1.f-fx);
    W16[(iy+1)*4 + ix+1] += wk * fy*fx;
  }
  int p = c >> 5, q = (c >> 3) & 3, j = c & 7;
  int n = o >> 4, m15 = o & 15;
  int lanei = q*16 + m15;
  for (int rs = 0; rs < 16; ++rs)
    wb2[(size_t)(((p*16 + rs)*4 + n)*64 + lanei)*8 + j] = f2bf(W16[rs]);
}

// ---------------------------------------------------------------------------
// conv: WG = 128 threads (2 waves), tile = 1 out row x 64 px x 64 Cout.
// Wave = 64 px x 32 Cout (wave index = Cout half), acc[4][2].
// LDS: 4 rows x 68 cols x 32 ch bf16, XOR slot swizzle. 17408 B -> 8 blk/CU.
// ---------------------------------------------------------------------------
__global__ __launch_bounds__(128, 4)   // 4 waves/EU -> 8 blocks/CU
void conv_mfma(const float* __restrict__ x,
               const unsigned short* __restrict__ wb2,
               float* __restrict__ out)
{
  __shared__ __align__(16) unsigned short tile[4 * NC * 32]; // 17408 B

  const int wg  = blockIdx.x;                   // 2048
  const int xcd = wg & 7;
  const int i   = wg >> 3;                      // 0..255
  const int b   = i >> 5;                       // 0..7
  const int r5  = i & 31;
  const int y0  = xcd * 16 + (r5 >> 1);         // XCD-local 16-row band
  const int x0  = (r5 & 1) * 64;                // x half
  const int t    = threadIdx.x;
  const int wave = t >> 6;                      // 0..1: Cout half
  const int lane = t & 63;
  const int m15  = lane & 15;
  const int q    = lane >> 4;
  const int wv   = __builtin_amdgcn_readfirstlane(wave);

  // ---- per-lane staging constants ----
  int gx   = x0 - 1 + lane;
  bool gxv = ((unsigned)gx < (unsigned)WW);
  int gxc  = gx < 0 ? 0 : (gx > WW-1 ? WW-1 : gx);
  int gxh  = x0 + 63 + lane;                    // halo cols 64..66 (lanes 0..2)
  bool gxhv = ((unsigned)gxh < (unsigned)WW);
  int gxhc = gxh < 0 ? 0 : (gxh > WW-1 ? WW-1 : gxh);

  // LDS store bases: cell(row,col,slot) at row*4352 + col*64 + slot*16 bytes,
  // slot = (chunk + (col>>2)) & 3. Wave's chunks are {wv, wv+2} (j = it&1).
  // Halo col = 64+lane: (64+lane)>>2 == (lane>>2)+16 -> same slot phase,
  // address = main + 4096.
  const int w4 = (lane >> 2) & 3;
  char* pst[2];
  pst[0] = (char*)tile + lane*64 + ((wv     + w4) & 3)*16;
  pst[1] = (char*)tile + lane*64 + ((wv + 2 + w4) & 3)*16;

  // A-fragment read pointers: c = mi*16 + m15 + s; slot phase invariant under
  // mi*16 -> aptr[s] + r*4352 + mi*1024 (all-immediate offsets in the rs loop).
  const char* aptr[4];
  #pragma unroll
  for (int s = 0; s < 4; ++s) {
    int c0   = m15 + s;
    int slot = (q + (c0 >> 2)) & 3;
    aptr[s] = (const char*)tile + c0*64 + slot*16;
  }

  f32x4 acc[4][2];
  #pragma unroll
  for (int mi = 0; mi < 4; ++mi)
    #pragma unroll
    for (int nn = 0; nn < 2; ++nn)
      acc[mi][nn] = (f32x4){0.f, 0.f, 0.f, 0.f};

  #pragma unroll
  for (int p = 0; p < 2; ++p) {                 // channel pass: c in [32p, 32p+32)
    if (p) __syncthreads();                     // pass-0 tile reads complete

    // ---- stage: 8 items/wave = 4 rows x 2 chunks(8ch) ----
    #pragma unroll
    for (int it = 0; it < 8; ++it) {
      const int row   = it >> 1;
      const int j     = it & 1;
      const int chunk = wv + 2*j;               // uniform
      const int gy    = y0 + row - 1;           // uniform, -1..129
      char* dst = pst[j] + row*4352;
      if ((unsigned)gy < (unsigned)HH) {        // scalar branch
        const float* ps = x + ((size_t)((b*CIN + p*32 + chunk*8)*HH + gy))*WW;
        float v[8];
        #pragma unroll
        for (int cc = 0; cc < 8; ++cc) v[cc] = ps[(size_t)cc*HH*WW + gxc];
        unsigned int pk[4];
        #pragma unroll
        for (int ii = 0; ii < 4; ++ii) {
          pk[ii] = cvtpk(v[2*ii], v[2*ii+1]);
          pk[ii] = gxv ? pk[ii] : 0u;           // zero-pad col gx==-1/128/129
        }
        *(u32x4*)dst = *(u32x4*)pk;
        if (lane < 3) {                         // halo cols 64..66
          float vh[8];
          #pragma unroll
          for (int cc = 0; cc < 8; ++cc) vh[cc] = ps[(size_t)cc*HH*WW + gxhc];
          unsigned int ph[4];
          #pragma unroll
          for (int ii = 0; ii < 4; ++ii) {
            ph[ii] = cvtpk(vh[2*ii], vh[2*ii+1]);
            ph[ii] = gxhv ? ph[ii] : 0u;
          }
          *(u32x4*)(dst + 4096) = *(u32x4*)ph;
        }
      } else if (p == 0) {                      // OOB row: zero once; pass 1 keeps it
        *(u32x4*)dst = (u32x4){0u,0u,0u,0u};
        if (lane < 3) *(u32x4*)(dst + 4096) = (u32x4){0u,0u,0u,0u};
      }
    }
    __syncthreads();

    // ---- compute: 16 rs steps; B = stream loads, A = imm-offset LDS reads ----
    const char* wp = (const char*)wb2 + (size_t)p*65536 + wave*2048 + (size_t)lane*16;
    #pragma unroll
    for (int rs = 0; rs < 16; ++rs) {
      const int r = rs >> 2, s = rs & 3;
      bf16x8 bfr[2];
      bfr[0] = *(const bf16x8*)(wp + rs*4096);
      bfr[1] = *(const bf16x8*)(wp + rs*4096 + 1024);
      bf16x8 afr[4];
      #pragma unroll
      for (int mi = 0; mi < 4; ++mi)
        afr[mi] = *(const bf16x8*)(aptr[s] + r*4352 + mi*1024);
      #pragma unroll
      for (int mi = 0; mi < 4; ++mi)
        #pragma unroll
        for (int nn = 0; nn < 2; ++nn)
          acc[mi][nn] = __builtin_amdgcn_mfma_f32_16x16x32_bf16(afr[mi], bfr[nn], acc[mi][nn], 0, 0, 0);
    }
  }

  // ---- epilogue: transpose through LDS for coalesced f32x4 stores ----
  __syncthreads();                              // all tile reads done
  float* epi = (float*)tile;                    // [64 o][68 px] f32 = 17408 B
  #pragma unroll
  for (int mi = 0; mi < 4; ++mi)
    #pragma unroll
    for (int nn = 0; nn < 2; ++nn) {
      int o  = (wave*2 + nn)*16 + m15;
      int px = mi*16 + q*4;                     // D row = q*4 + reg
      *(f32x4*)&epi[o*NC + px] = acc[mi][nn];
    }
  __syncthreads();
  #pragma unroll
  for (int round = 0; round < 8; ++round) {
    int idx = round*512 + t*4;                  // 64 o x 64 px
    int o = idx >> 6, px = idx & 63;
    f32x4 v = *(const f32x4*)&epi[o*NC + px];
    *(f32x4*)&out[(((size_t)(b*COUT + o))*HH + y0)*WW + x0 + px] = v;
  }
}

// ---------------------------------------------------------------------------
extern "C" void kernel_launch(void* const* d_in, const int* in_sizes, int n_in,
                              void* d_out, int out_size, void* d_ws, size_t ws_size,
                              hipStream_t stream)
{
  const float* x   = (const float*)d_in[0];   // [8,64,128,128] fp32
  const float* wgt = (const float*)d_in[1];   // [64,64,9] fp32
  const float* off = (const float*)d_in[2];   // [9,2] fp32
  float* out = (float*)d_out;                 // [8,64,128,128] fp32
  unsigned short* wb2 = (unsigned short*)d_ws;// 128 KB stream-layout weights

  make_wb<<<64, 64, 0, stream>>>(wgt, off, wb2);
  conv_mfma<<<2048, 128, 0, stream>>>(x, wb2, out);
}